// Round 1
// baseline (302.250 us; speedup 1.0000x reference)
//
#include <hip/hip_runtime.h>

#define L_SEQ 1024
#define EMB 1024
#define NH 16
#define HD 64

constexpr float SCALE = 0.03125f;      // 1/sqrt(1024)
constexpr float MASK_FILL = -1000.0f;

typedef _Float16 half8 __attribute__((ext_vector_type(8)));
typedef _Float16 half4v __attribute__((ext_vector_type(4)));
typedef float f32x4 __attribute__((ext_vector_type(4)));
typedef float fvec4 __attribute__((ext_vector_type(4)));

constexpr int LP = 72;  // attn LDS pitch (f16 elems): 144 B rows, 16B-aligned
constexpr int FP = 40;  // fc LDS pitch: 80 B rows, 16B-aligned, 2-way bank alias only

// ---------------------------------------------------------------------------
// Prepass: pack attn_mask (L*L int32, 0/1) into bitmask words (L * L/32)
// ---------------------------------------------------------------------------
__global__ void pack_mask_kernel(const int* __restrict__ am, unsigned* __restrict__ bits) {
    int w = blockIdx.x * blockDim.x + threadIdx.x;   // 32768 words
    const int* p = am + (size_t)w * 32;
    unsigned b = 0;
#pragma unroll
    for (int i = 0; i < 32; ++i) b |= (p[i] != 0 ? 1u : 0u) << i;
    bits[w] = b;
}

// ---------------------------------------------------------------------------
// Prepass: fc_w fp32 -> f16
// ---------------------------------------------------------------------------
__global__ void convert_w_kernel(const float* __restrict__ w, _Float16* __restrict__ o) {
    size_t i = ((size_t)blockIdx.x * blockDim.x + threadIdx.x) * 4;
    fvec4 v = *(const fvec4*)(w + i);
    half4v h;
#pragma unroll
    for (int j = 0; j < 4; ++j) h[j] = (_Float16)v[j];
    *(half4v*)(o + i) = h;
}

// ---------------------------------------------------------------------------
// Fused masked attention (flash-style, online softmax).
// grid: (L/64, NH, N), block 256 (4 waves). Wave w owns q-rows w*16..w*16+15.
// Writes f16 attention output in (n, q, e=h*64+d) layout to ws.
// ---------------------------------------------------------------------------
__global__ __launch_bounds__(256) void attn_kernel(
    const float* __restrict__ values, const float* __restrict__ keys,
    const float* __restrict__ queries, const unsigned* __restrict__ mbits,
    const int* __restrict__ pad_mask, _Float16* __restrict__ out_f16)
{
    __shared__ __align__(16) _Float16 K_lds[64 * LP];
    __shared__ __align__(16) _Float16 Vt_lds[64 * LP];
    __shared__ __align__(16) _Float16 P_lds[64 * LP];
    __shared__ int s_pad[64];

    const int tid  = threadIdx.x;
    const int lane = tid & 63;
    const int wave = tid >> 6;
    const int l16  = lane & 15;
    const int quad = lane >> 4;
    const int qt = blockIdx.x, h = blockIdx.y, n = blockIdx.z;
    const int qbase = qt * 64;

    // --- Q fragments (A operand): rows wave*16 + l16, k = t*32 + quad*8 + j
    const int qrow_frag = qbase + wave * 16 + l16;
    const float* qp = queries + ((size_t)n * L_SEQ + qrow_frag) * EMB + h * HD;
    half8 qf[2];
#pragma unroll
    for (int t = 0; t < 2; ++t) {
        fvec4 v0 = *(const fvec4*)(qp + t * 32 + quad * 8);
        fvec4 v1 = *(const fvec4*)(qp + t * 32 + quad * 8 + 4);
#pragma unroll
        for (int j = 0; j < 4; ++j) { qf[t][j] = (_Float16)v0[j]; qf[t][j + 4] = (_Float16)v1[j]; }
    }

    f32x4 Ov[4];                 // O accumulator, C-layout: col dv=dt*16+l16, row quad*4+reg
#pragma unroll
    for (int dt = 0; dt < 4; ++dt) Ov[dt] = (f32x4){0.f, 0.f, 0.f, 0.f};
    float m_i[4], l_i[4];
#pragma unroll
    for (int r = 0; r < 4; ++r) { m_i[r] = -3.0e38f; l_i[r] = 0.f; }

    const int r_st = tid >> 2;              // staging row 0..63
    const int cbase = (tid & 3) * 16;       // staging col chunk

    for (int kt = 0; kt < L_SEQ / 64; ++kt) {
        const int kbase = kt * 64;
        __syncthreads();   // prev-iter LDS reads done before overwrite

        // --- stage K tile (row-major) and V tile (transposed) as f16
        {
            const float* kp = keys + ((size_t)n * L_SEQ + kbase + r_st) * EMB + h * HD + cbase;
            fvec4 k0 = *(const fvec4*)(kp);
            fvec4 k1 = *(const fvec4*)(kp + 4);
            fvec4 k2 = *(const fvec4*)(kp + 8);
            fvec4 k3 = *(const fvec4*)(kp + 12);
            half8 h0, h1;
#pragma unroll
            for (int j = 0; j < 4; ++j) {
                h0[j] = (_Float16)k0[j]; h0[j + 4] = (_Float16)k1[j];
                h1[j] = (_Float16)k2[j]; h1[j + 4] = (_Float16)k3[j];
            }
            *(half8*)(&K_lds[r_st * LP + cbase]) = h0;
            *(half8*)(&K_lds[r_st * LP + cbase + 8]) = h1;

            const float* vp = values + ((size_t)n * L_SEQ + kbase + r_st) * EMB + h * HD + cbase;
            fvec4 vv[4];
            vv[0] = *(const fvec4*)(vp);
            vv[1] = *(const fvec4*)(vp + 4);
            vv[2] = *(const fvec4*)(vp + 8);
            vv[3] = *(const fvec4*)(vp + 12);
#pragma unroll
            for (int i = 0; i < 16; ++i)
                Vt_lds[(cbase + i) * LP + r_st] = (_Float16)vv[i >> 2][i & 3];

            if (tid < 64) s_pad[tid] = pad_mask[(size_t)n * L_SEQ + kbase + tid];
        }
        __syncthreads();

        // --- S = Q * K^T  (16x64 strip per wave)
        f32x4 Sacc[4];
#pragma unroll
        for (int tj = 0; tj < 4; ++tj) Sacc[tj] = (f32x4){0.f, 0.f, 0.f, 0.f};
#pragma unroll
        for (int t = 0; t < 2; ++t) {
#pragma unroll
            for (int tj = 0; tj < 4; ++tj) {
                half8 bf = *(const half8*)(&K_lds[(tj * 16 + l16) * LP + t * 32 + quad * 8]);
                Sacc[tj] = __builtin_amdgcn_mfma_f32_16x16x32_f16(qf[t], bf, Sacc[tj], 0, 0, 0);
            }
        }

        // --- mask + scale
        int pok[4];
#pragma unroll
        for (int tj = 0; tj < 4; ++tj) pok[tj] = s_pad[tj * 16 + l16];

        float z[4][4];   // [reg][tj]
#pragma unroll
        for (int reg = 0; reg < 4; ++reg) {
            const int qrow = qbase + wave * 16 + quad * 4 + reg;
            const unsigned w0 = mbits[(qrow << 5) + (kbase >> 5)];
            const unsigned w1 = mbits[(qrow << 5) + (kbase >> 5) + 1];
#pragma unroll
            for (int tj = 0; tj < 4; ++tj) {
                const int kl = tj * 16 + l16;
                const unsigned wbits = (tj < 2) ? w0 : w1;
                const int ok = ((wbits >> (kl & 31)) & 1u) && pok[tj];
                z[reg][tj] = (ok ? Sacc[tj][reg] : MASK_FILL) * SCALE;
            }
        }

        // --- online softmax update
#pragma unroll
        for (int reg = 0; reg < 4; ++reg) {
            float mx = fmaxf(fmaxf(z[reg][0], z[reg][1]), fmaxf(z[reg][2], z[reg][3]));
            mx = fmaxf(mx, __shfl_xor(mx, 1));
            mx = fmaxf(mx, __shfl_xor(mx, 2));
            mx = fmaxf(mx, __shfl_xor(mx, 4));
            mx = fmaxf(mx, __shfl_xor(mx, 8));
            const float m_new = fmaxf(m_i[reg], mx);
            const float al = __expf(m_i[reg] - m_new);
            m_i[reg] = m_new;
            float rs = 0.f;
#pragma unroll
            for (int tj = 0; tj < 4; ++tj) {
                const float pv = __expf(z[reg][tj] - m_new);
                z[reg][tj] = pv;
                rs += pv;
            }
            rs += __shfl_xor(rs, 1);
            rs += __shfl_xor(rs, 2);
            rs += __shfl_xor(rs, 4);
            rs += __shfl_xor(rs, 8);
            l_i[reg] = l_i[reg] * al + rs;
#pragma unroll
            for (int dt = 0; dt < 4; ++dt) Ov[dt][reg] *= al;
        }

        // --- P -> LDS (C-layout positions), then read back as A-operand frags
#pragma unroll
        for (int reg = 0; reg < 4; ++reg)
#pragma unroll
            for (int tj = 0; tj < 4; ++tj)
                P_lds[(wave * 16 + quad * 4 + reg) * LP + tj * 16 + l16] = (_Float16)z[reg][tj];
        __syncthreads();

        // --- O += P * V
#pragma unroll
        for (int t = 0; t < 2; ++t) {
            half8 af = *(const half8*)(&P_lds[(wave * 16 + l16) * LP + t * 32 + quad * 8]);
#pragma unroll
            for (int dt = 0; dt < 4; ++dt) {
                half8 bf = *(const half8*)(&Vt_lds[(dt * 16 + l16) * LP + t * 32 + quad * 8]);
                Ov[dt] = __builtin_amdgcn_mfma_f32_16x16x32_f16(af, bf, Ov[dt], 0, 0, 0);
            }
        }
    }

    // --- epilogue: O /= l, store f16 (n, q, h*64+dv)
#pragma unroll
    for (int reg = 0; reg < 4; ++reg) {
        const float inv = 1.0f / l_i[reg];
        const int qrow = qbase + wave * 16 + quad * 4 + reg;
        _Float16* op = out_f16 + ((size_t)n * L_SEQ + qrow) * EMB + h * HD;
#pragma unroll
        for (int dt = 0; dt < 4; ++dt)
            op[dt * 16 + l16] = (_Float16)(Ov[dt][reg] * inv);
    }
}

// ---------------------------------------------------------------------------
// FC: C[8192][1024] = A[8192][1024](f16) * W^T (W[1024][1024] f16) + bias
// grid (64, 8), block 256. 128x128 tile, BK=32, 4 waves in 2x2.
// ---------------------------------------------------------------------------
__global__ __launch_bounds__(256) void fc_kernel(
    const _Float16* __restrict__ A, const _Float16* __restrict__ W,
    const float* __restrict__ bias, float* __restrict__ C)
{
    __shared__ __align__(16) _Float16 As[128 * FP];
    __shared__ __align__(16) _Float16 Ws[128 * FP];

    const int tid  = threadIdx.x;
    const int lane = tid & 63;
    const int wv   = tid >> 6;
    const int l16  = lane & 15;
    const int quad = lane >> 4;
    const int wm = (wv >> 1) * 64, wn = (wv & 1) * 64;
    const int Mb = blockIdx.x * 128, Nb = blockIdx.y * 128;

    f32x4 acc[4][4];
#pragma unroll
    for (int i = 0; i < 4; ++i)
#pragma unroll
        for (int j = 0; j < 4; ++j) acc[i][j] = (f32x4){0.f, 0.f, 0.f, 0.f};

    for (int k0 = 0; k0 < EMB; k0 += 32) {
        __syncthreads();
#pragma unroll
        for (int s = 0; s < 2; ++s) {
            const int id = tid + s * 256;          // 0..511
            const int row = id >> 2, ch = (id & 3) * 8;
            *(half8*)(&As[row * FP + ch]) = *(const half8*)(A + (size_t)(Mb + row) * EMB + k0 + ch);
            *(half8*)(&Ws[row * FP + ch]) = *(const half8*)(W + (size_t)(Nb + row) * EMB + k0 + ch);
        }
        __syncthreads();

        half8 af[4], bf[4];
#pragma unroll
        for (int i = 0; i < 4; ++i) {
            af[i] = *(const half8*)(&As[(wm + i * 16 + l16) * FP + quad * 8]);
            bf[i] = *(const half8*)(&Ws[(wn + i * 16 + l16) * FP + quad * 8]);
        }
#pragma unroll
        for (int i = 0; i < 4; ++i)
#pragma unroll
            for (int j = 0; j < 4; ++j)
                acc[i][j] = __builtin_amdgcn_mfma_f32_16x16x32_f16(af[i], bf[j], acc[i][j], 0, 0, 0);
    }

    // epilogue: + bias, fp32 store
#pragma unroll
    for (int i = 0; i < 4; ++i) {
        const int m = Mb + wm + i * 16 + quad * 4;
#pragma unroll
        for (int j = 0; j < 4; ++j) {
            const int jc = Nb + wn + j * 16 + l16;
            const float b = bias[jc];
#pragma unroll
            for (int reg = 0; reg < 4; ++reg)
                C[(size_t)(m + reg) * EMB + jc] = acc[i][j][reg] + b;
        }
    }
}

// ---------------------------------------------------------------------------
extern "C" void kernel_launch(void* const* d_in, const int* in_sizes, int n_in,
                              void* d_out, int out_size, void* d_ws, size_t ws_size,
                              hipStream_t stream) {
    const float* values  = (const float*)d_in[0];
    const float* keys    = (const float*)d_in[1];
    const float* queries = (const float*)d_in[2];
    const float* fc_w    = (const float*)d_in[3];
    const float* fc_b    = (const float*)d_in[4];
    const int*   amask   = (const int*)d_in[5];
    const int*   pmask   = (const int*)d_in[6];
    float* out = (float*)d_out;

    // ws layout: [0,16MB) attn out f16; [16MB,18MB) W f16; [18MB,+128KB) mask bits
    _Float16* attn_out = (_Float16*)d_ws;
    _Float16* w_f16    = (_Float16*)((char*)d_ws + (size_t)8 * 1024 * 1024 * 2);
    unsigned* mbits    = (unsigned*)((char*)d_ws + (size_t)8 * 1024 * 1024 * 2 + (size_t)1024 * 1024 * 2);

    pack_mask_kernel<<<128, 256, 0, stream>>>(amask, mbits);
    convert_w_kernel<<<1024, 256, 0, stream>>>(fc_w, w_f16);
    attn_kernel<<<dim3(L_SEQ / 64, NH, 8), 256, 0, stream>>>(values, keys, queries, mbits, pmask, attn_out);
    fc_kernel<<<dim3(64, 8), 256, 0, stream>>>(attn_out, w_f16, fc_b, out);
}

// Round 2
// 240.676 us; speedup vs baseline: 1.2558x; 1.2558x over previous
//
#include <hip/hip_runtime.h>

#define L_SEQ 1024
#define EMB 1024
#define NH 16
#define HD 64

typedef _Float16 half8 __attribute__((ext_vector_type(8)));
typedef _Float16 half4v __attribute__((ext_vector_type(4)));
typedef float f32x4 __attribute__((ext_vector_type(4)));
typedef float fvec4 __attribute__((ext_vector_type(4)));
typedef unsigned int u32;
typedef unsigned long long u64;

constexpr float C2 = 0.045084220027780106f;   // SCALE * log2(e)
constexpr float F2 = -45.08422002778011f;     // MASK_FILL * SCALE * log2(e)

constexpr int FP = 40;   // fc LDS pitch
constexpr int PP = 72;   // P_lds pitch (144 B rows: 16B-aligned, 2-way bank alias only)

__device__ __forceinline__ void async16(const void* g, void* l) {
    __builtin_amdgcn_global_load_lds((const __attribute__((address_space(1))) u32*)g,
                                     (__attribute__((address_space(3))) u32*)l, 16, 0, 0);
}

// ---------------------------------------------------------------------------
// Prepass: pack attn_mask into bitmask via wave ballot (fully coalesced)
// ---------------------------------------------------------------------------
__global__ void pack_mask_kernel(const int* __restrict__ am, u32* __restrict__ bits) {
    const int i = blockIdx.x * 256 + threadIdx.x;
    const int lane = threadIdx.x & 63;
    u64 b = __ballot(am[i] != 0);
    if (lane == 0)       bits[i >> 5] = (u32)b;
    else if (lane == 32) bits[i >> 5] = (u32)(b >> 32);
}

// ---------------------------------------------------------------------------
// Prepass: fc_w fp32 -> f16
// ---------------------------------------------------------------------------
__global__ void convert_w_kernel(const float* __restrict__ w, _Float16* __restrict__ o) {
    size_t i = ((size_t)blockIdx.x * blockDim.x + threadIdx.x) * 4;
    fvec4 v = *(const fvec4*)(w + i);
    half4v h;
#pragma unroll
    for (int j = 0; j < 4; ++j) h[j] = (_Float16)v[j];
    *(half4v*)(o + i) = h;
}

// ---------------------------------------------------------------------------
// Prepass: K -> f16 head-blocked (nh, k, d); V -> f16 transposed (nh, d, k)
// grid (16 kt, 16 h, 8 n), 256 threads
// ---------------------------------------------------------------------------
__global__ __launch_bounds__(256) void cvt_kv_kernel(
    const float* __restrict__ keys, const float* __restrict__ values,
    _Float16* __restrict__ K16, _Float16* __restrict__ Vt16)
{
    __shared__ __align__(16) _Float16 Vt[64 * PP];
    const int tid = threadIdx.x;
    const int kt = blockIdx.x, h = blockIdx.y, n = blockIdx.z;
    const int kbase = kt * 64;
    const int r = tid >> 2, c0 = (tid & 3) * 16;
    const int nh = n * NH + h;

    {   // K: reorder rows into head-blocked, convert
        const float* src = keys + ((size_t)(n * L_SEQ + kbase + r)) * EMB + h * HD + c0;
        fvec4 a0 = *(const fvec4*)(src),     a1 = *(const fvec4*)(src + 4);
        fvec4 a2 = *(const fvec4*)(src + 8), a3 = *(const fvec4*)(src + 12);
        half8 o0, o1;
#pragma unroll
        for (int j = 0; j < 4; ++j) {
            o0[j] = (_Float16)a0[j]; o0[j + 4] = (_Float16)a1[j];
            o1[j] = (_Float16)a2[j]; o1[j + 4] = (_Float16)a3[j];
        }
        _Float16* dst = K16 + ((size_t)nh * L_SEQ + kbase + r) * HD + c0;
        *(half8*)dst = o0; *(half8*)(dst + 8) = o1;
    }
    {   // V: stage transposed tile in LDS
        const float* src = values + ((size_t)(n * L_SEQ + kbase + r)) * EMB + h * HD + c0;
        fvec4 vv[4];
        vv[0] = *(const fvec4*)(src);     vv[1] = *(const fvec4*)(src + 4);
        vv[2] = *(const fvec4*)(src + 8); vv[3] = *(const fvec4*)(src + 12);
#pragma unroll
        for (int i = 0; i < 16; ++i)
            Vt[(c0 + i) * PP + r] = (_Float16)vv[i >> 2][i & 3];
    }
    __syncthreads();
    {   // write Vt16 rows (d-major)
        const int d = tid >> 2, k0 = (tid & 3) * 16;
        half8 v0 = *(const half8*)(&Vt[d * PP + k0]);
        half8 v1 = *(const half8*)(&Vt[d * PP + k0 + 8]);
        _Float16* dst = Vt16 + ((size_t)nh * HD + d) * L_SEQ + kbase + k0;
        *(half8*)dst = v0; *(half8*)(dst + 8) = v1;
    }
}

// ---------------------------------------------------------------------------
// Fused masked attention, S^T formulation, no max-tracking.
// grid 1024 (bid = nh + 128*qt -> qt-blocks of same (n,h) share an XCD),
// block 256 (4 waves), qtile=128 (32 q / wave), ktile=64.
// ---------------------------------------------------------------------------
__global__ __launch_bounds__(256, 4) void attn_kernel(
    const _Float16* __restrict__ K16, const _Float16* __restrict__ Vt16,
    const float* __restrict__ queries, const u32* __restrict__ mbits,
    const int* __restrict__ pad_mask, _Float16* __restrict__ out_f16)
{
    __shared__ __align__(16) _Float16 K_lds[64 * 64];   // unpadded (DMA), XOR-swizzled
    __shared__ __align__(16) _Float16 V_lds[64 * 64];   // V^T tile, XOR-swizzled
    __shared__ __align__(16) _Float16 P_lds[128 * PP];

    const int tid = threadIdx.x;
    const int lane = tid & 63;
    const int wave = tid >> 6;
    const int l16 = lane & 15;
    const int quad = lane >> 4;
    const int bid = blockIdx.x;
    const int nh = bid & 127, qt = bid >> 7;
    const int n = nh >> 4, h = nh & 15;
    const int qbase = qt * 128;
    const int xr = l16 & 7;

    // --- Q fragments (B operand for S^T): strip s rows qbase+wave*32+s*16+l16
    half8 qf[2][2];
#pragma unroll
    for (int s = 0; s < 2; ++s) {
        const int qrow = qbase + wave * 32 + s * 16 + l16;
        const float* qp = queries + ((size_t)(n * L_SEQ + qrow)) * EMB + h * HD;
#pragma unroll
        for (int t = 0; t < 2; ++t) {
            fvec4 a = *(const fvec4*)(qp + t * 32 + quad * 8);
            fvec4 b = *(const fvec4*)(qp + t * 32 + quad * 8 + 4);
#pragma unroll
            for (int j = 0; j < 4; ++j) { qf[s][t][j] = (_Float16)a[j]; qf[s][t][j + 4] = (_Float16)b[j]; }
        }
    }

    f32x4 Ov[2][4];
#pragma unroll
    for (int s = 0; s < 2; ++s)
#pragma unroll
        for (int dt = 0; dt < 4; ++dt) Ov[s][dt] = (f32x4){0.f, 0.f, 0.f, 0.f};
    float lsum[2] = {0.f, 0.f};

    const _Float16* Kt_base = K16 + (size_t)nh * L_SEQ * HD;
    const _Float16* Vt_base = Vt16 + (size_t)nh * HD * L_SEQ;
    const int gch = (lane & 7) ^ ((lane >> 3) & 7);      // XOR-swizzled source chunk

    for (int kt = 0; kt < L_SEQ / 64; ++kt) {
        const int kbase = kt * 64;
        // mask words (global, issued early)
        u32 w0[2], w1[2];
#pragma unroll
        for (int s = 0; s < 2; ++s) {
            const int qrow = qbase + wave * 32 + s * 16 + l16;
            w0[s] = mbits[qrow * 32 + kt * 2];
            w1[s] = mbits[qrow * 32 + kt * 2 + 1];
        }
        const u64 bal = __ballot(pad_mask[(size_t)n * L_SEQ + kbase + lane] != 0);
        const u32 plo = (u32)bal, phi = (u32)(bal >> 32);

        __syncthreads();   // prior-iter LDS reads complete
#pragma unroll
        for (int s2 = 0; s2 < 2; ++s2) {   // DMA stage K + Vt (8 rows / inst / wave)
            const int row = wave * 16 + s2 * 8 + (lane >> 3);
            async16(Kt_base + (size_t)(kbase + row) * HD + gch * 8, &K_lds[(wave * 16 + s2 * 8) * 64]);
            async16(Vt_base + (size_t)row * L_SEQ + kbase + gch * 8, &V_lds[(wave * 16 + s2 * 8) * 64]);
        }
        __syncthreads();   // staged data visible

        // --- S^T = K * Q^T (swapped operands: A=K frag, B=Q frag)
        f32x4 S[2][4];
#pragma unroll
        for (int s = 0; s < 2; ++s)
#pragma unroll
            for (int tj = 0; tj < 4; ++tj) S[s][tj] = (f32x4){0.f, 0.f, 0.f, 0.f};
#pragma unroll
        for (int tj = 0; tj < 4; ++tj) {
            const int krow = tj * 16 + l16;
            const _Float16* kr = &K_lds[krow * 64];
            const int c0 = (quad ^ xr) * 8;
            half8 k0 = *(const half8*)(kr + c0);
            half8 k1 = *(const half8*)(kr + (c0 ^ 32));
            S[0][tj] = __builtin_amdgcn_mfma_f32_16x16x32_f16(k0, qf[0][0], S[0][tj], 0, 0, 0);
            S[0][tj] = __builtin_amdgcn_mfma_f32_16x16x32_f16(k1, qf[0][1], S[0][tj], 0, 0, 0);
            S[1][tj] = __builtin_amdgcn_mfma_f32_16x16x32_f16(k0, qf[1][0], S[1][tj], 0, 0, 0);
            S[1][tj] = __builtin_amdgcn_mfma_f32_16x16x32_f16(k1, qf[1][1], S[1][tj], 0, 0, 0);
        }

        // --- masked exp2 (no max subtraction) + P write (b64, 4 consecutive k)
#pragma unroll
        for (int s = 0; s < 2; ++s) {
            const u32 pw0 = w0[s] & plo, pw1 = w1[s] & phi;
#pragma unroll
            for (int tj = 0; tj < 4; ++tj) {
                const u32 m4 = ((tj & 2) ? pw1 : pw0) >> ((tj & 1) * 16 + quad * 4);
                float p[4];
#pragma unroll
                for (int reg = 0; reg < 4; ++reg) {
                    const float e = ((m4 >> reg) & 1u) ? S[s][tj][reg] * C2 : F2;
                    p[reg] = __builtin_amdgcn_exp2f(e);
                }
                lsum[s] += (p[0] + p[1]) + (p[2] + p[3]);
                half4v hp = {(_Float16)p[0], (_Float16)p[1], (_Float16)p[2], (_Float16)p[3]};
                *(half4v*)(&P_lds[(wave * 32 + s * 16 + l16) * PP + tj * 16 + quad * 4]) = hp;
            }
        }

        // --- O += P * V  (P region is wave-private: no barrier needed)
        half8 pf0[2], pf1[2];
#pragma unroll
        for (int t = 0; t < 2; ++t) {
            pf0[t] = *(const half8*)(&P_lds[(wave * 32 + l16) * PP + t * 32 + quad * 8]);
            pf1[t] = *(const half8*)(&P_lds[(wave * 32 + 16 + l16) * PP + t * 32 + quad * 8]);
        }
#pragma unroll
        for (int t = 0; t < 2; ++t) {
            const int c0 = ((t * 4 + quad) ^ xr) * 8;
#pragma unroll
            for (int dt = 0; dt < 4; ++dt) {
                half8 vf = *(const half8*)(&V_lds[(dt * 16 + l16) * 64 + c0]);
                Ov[0][dt] = __builtin_amdgcn_mfma_f32_16x16x32_f16(pf0[t], vf, Ov[0][dt], 0, 0, 0);
                Ov[1][dt] = __builtin_amdgcn_mfma_f32_16x16x32_f16(pf1[t], vf, Ov[1][dt], 0, 0, 0);
            }
        }
    }

    // --- epilogue: reduce row-sums across quads (deferred), normalize, store
#pragma unroll
    for (int s = 0; s < 2; ++s) {
        lsum[s] += __shfl_xor(lsum[s], 16);
        lsum[s] += __shfl_xor(lsum[s], 32);
    }
#pragma unroll
    for (int s = 0; s < 2; ++s)
#pragma unroll
        for (int reg = 0; reg < 4; ++reg) {
            const float linv = 1.0f / __shfl(lsum[s], quad * 4 + reg);
            const int qrow = qbase + wave * 32 + s * 16 + quad * 4 + reg;
            _Float16* op = out_f16 + ((size_t)(n * L_SEQ + qrow)) * EMB + h * HD;
#pragma unroll
            for (int dt = 0; dt < 4; ++dt)
                op[dt * 16 + l16] = (_Float16)(Ov[s][dt][reg] * linv);
        }
}

// ---------------------------------------------------------------------------
// FC: C[8192][1024] = A(f16) * W^T(f16) + bias, 128x128 tile, BK=32
// ---------------------------------------------------------------------------
__global__ __launch_bounds__(256) void fc_kernel(
    const _Float16* __restrict__ A, const _Float16* __restrict__ W,
    const float* __restrict__ bias, float* __restrict__ C)
{
    __shared__ __align__(16) _Float16 As[128 * FP];
    __shared__ __align__(16) _Float16 Ws[128 * FP];

    const int tid = threadIdx.x;
    const int lane = tid & 63;
    const int wv = tid >> 6;
    const int l16 = lane & 15;
    const int quad = lane >> 4;
    const int wm = (wv >> 1) * 64, wn = (wv & 1) * 64;
    const int Mb = blockIdx.x * 128, Nb = blockIdx.y * 128;

    f32x4 acc[4][4];
#pragma unroll
    for (int i = 0; i < 4; ++i)
#pragma unroll
        for (int j = 0; j < 4; ++j) acc[i][j] = (f32x4){0.f, 0.f, 0.f, 0.f};

    for (int k0 = 0; k0 < EMB; k0 += 32) {
        __syncthreads();
#pragma unroll
        for (int s = 0; s < 2; ++s) {
            const int id = tid + s * 256;
            const int row = id >> 2, ch = (id & 3) * 8;
            *(half8*)(&As[row * FP + ch]) = *(const half8*)(A + (size_t)(Mb + row) * EMB + k0 + ch);
            *(half8*)(&Ws[row * FP + ch]) = *(const half8*)(W + (size_t)(Nb + row) * EMB + k0 + ch);
        }
        __syncthreads();

        half8 af[4], bf[4];
#pragma unroll
        for (int i = 0; i < 4; ++i) {
            af[i] = *(const half8*)(&As[(wm + i * 16 + l16) * FP + quad * 8]);
            bf[i] = *(const half8*)(&Ws[(wn + i * 16 + l16) * FP + quad * 8]);
        }
#pragma unroll
        for (int i = 0; i < 4; ++i)
#pragma unroll
            for (int j = 0; j < 4; ++j)
                acc[i][j] = __builtin_amdgcn_mfma_f32_16x16x32_f16(af[i], bf[j], acc[i][j], 0, 0, 0);
    }

#pragma unroll
    for (int i = 0; i < 4; ++i) {
        const int m = Mb + wm + i * 16 + quad * 4;
#pragma unroll
        for (int j = 0; j < 4; ++j) {
            const int jc = Nb + wn + j * 16 + l16;
            const float b = bias[jc];
#pragma unroll
            for (int reg = 0; reg < 4; ++reg)
                C[(size_t)(m + reg) * EMB + jc] = acc[i][j][reg] + b;
        }
    }
}

// ---------------------------------------------------------------------------
extern "C" void kernel_launch(void* const* d_in, const int* in_sizes, int n_in,
                              void* d_out, int out_size, void* d_ws, size_t ws_size,
                              hipStream_t stream) {
    const float* values  = (const float*)d_in[0];
    const float* keys    = (const float*)d_in[1];
    const float* queries = (const float*)d_in[2];
    const float* fc_w    = (const float*)d_in[3];
    const float* fc_b    = (const float*)d_in[4];
    const int*   amask   = (const int*)d_in[5];
    const int*   pmask   = (const int*)d_in[6];
    float* out = (float*)d_out;

    // ws: [0,16M) attn_out f16 | [16M,18M) W f16 | [18M,+128K) mbits |
    //     [19M,35M) K16 | [35M,51M) Vt16
    char* w = (char*)d_ws;
    _Float16* attn_out = (_Float16*)w;
    _Float16* w_f16    = (_Float16*)(w + (size_t)16 * 1024 * 1024);
    u32*      mbits    = (u32*)(w + (size_t)18 * 1024 * 1024);
    _Float16* K16      = (_Float16*)(w + (size_t)19 * 1024 * 1024);
    _Float16* Vt16     = (_Float16*)(w + (size_t)35 * 1024 * 1024);

    pack_mask_kernel<<<4096, 256, 0, stream>>>(amask, mbits);
    convert_w_kernel<<<1024, 256, 0, stream>>>(fc_w, w_f16);
    cvt_kv_kernel<<<dim3(16, 16, 8), 256, 0, stream>>>(keys, values, K16, Vt16);
    attn_kernel<<<1024, 256, 0, stream>>>(K16, Vt16, queries, mbits, pmask, attn_out);
    fc_kernel<<<dim3(64, 8), 256, 0, stream>>>(attn_out, w_f16, fc_b, out);
}